// Round 2
// baseline (125.327 us; speedup 1.0000x reference)
//
#include <hip/hip_runtime.h>

// Problem constants (from reference)
constexpr int B_  = 16;
constexpr int A_  = 3;     // MASK_SIZE
constexpr int C_  = 80;    // NUM_CLASSES
constexpr int T_  = 50;    // MAX_BOXES
constexpr int H_  = 76;
constexpr int W_  = 76;
constexpr int HW_ = H_ * W_;                  // 5776
constexpr int BSTR_ = A_ * (5 + C_) * HW_;    // 1472880 elements per batch
constexpr float NETW_ = 608.0f;
constexpr float NETH_ = 608.0f;

constexpr int NB_          = 256;             // total blocks in yolo_main
constexpr int F4_PER_SLICE = HW_ / 4;         // 1444 float4 per conf plane
constexpr int CONF_F4      = B_ * A_ * F4_PER_SLICE;  // 69312
constexpr int NBCE_        = B_ * T_ * C_;    // 64000 (b,t,c) triples

__device__ const float ANCH[18] = {
    10.f, 13.f, 16.f, 30.f, 33.f, 23.f, 30.f, 61.f, 62.f,
    45.f, 59.f, 119.f, 116.f, 90.f, 156.f, 198.f, 373.f, 326.f};

__device__ __forceinline__ float sigf(float z) {
    return 1.0f / (1.0f + expf(-z));
}

__device__ __forceinline__ float waveRed(float v) {
    #pragma unroll
    for (int o = 32; o > 0; o >>= 1) v += __shfl_down(v, o);
    return v;
}

// Shared assignment computation: returns true if target (b,t) is assigned,
// fills besti/gi/gj. Must match reference argmax (first strict max wins).
__device__ __forceinline__ bool assign_target(const float* __restrict__ tgt,
                                              int b, int t,
                                              float& tc, float& tx, float& ty,
                                              float& tw, float& th,
                                              int& besti, int& gi, int& gj) {
    const float* tp = tgt + (b * T_ + t) * 5;
    tc = tp[0]; tx = tp[1]; ty = tp[2]; tw = tp[3]; th = tp[4];
    const bool valid = (tc + tx + ty + tw + th) != 0.0f;

    float bestv = -1.0f;
    besti = 0;
    #pragma unroll
    for (int k = 0; k < 9; ++k) {
        const float aw = ANCH[2 * k]     * (1.0f / NETW_);
        const float ah = ANCH[2 * k + 1] * (1.0f / NETH_);
        const float in = fminf(tw, aw) * fminf(th, ah);
        const float un = tw * th + aw * ah - in;
        const float iou = in / un;
        if (iou > bestv) { bestv = iou; besti = k; }
    }
    if (!(valid && besti < A_)) return false;

    gi = (int)(tx * (float)W_);
    gi = gi < 0 ? 0 : (gi > W_ - 1 ? W_ - 1 : gi);
    gj = (int)(ty * (float)H_);
    gj = gj < 0 ? 0 : (gj > H_ - 1 ? H_ - 1 : gj);
    return true;
}

// ws layout (floats):
//  [0..15]   lcoord per batch
//  [32..47]  valid count per batch
//  [48..63]  unique assigned-cell count per batch
//  [64..64+NB_)  per-block combined (conf-sigmoid-sum + BCE) partials
__global__ __launch_bounds__(256) void yolo_main(const float* __restrict__ inp,
                                                 const float* __restrict__ tgt,
                                                 float* __restrict__ ws) {
    const int tid = threadIdx.x;
    const int bid = blockIdx.x;
    const int gt  = bid * 256 + tid;
    constexpr int GT = NB_ * 256;  // 65536 threads

    float acc = 0.0f;  // conf sum + BCE, combined (both enter the loss additively)

    // ---------- conf-channel sigmoid sum (whole grid) ----------
    for (int f = gt; f < CONF_F4; f += GT) {
        const int sl   = f / F4_PER_SLICE;
        const int pos4 = f - sl * F4_PER_SLICE;
        const int b    = sl / A_;
        const int a    = sl - b * A_;
        const float4 v = *reinterpret_cast<const float4*>(
            inp + b * BSTR_ + (a * 85 + 4) * HW_ + pos4 * 4);
        acc += sigf(v.x) + sigf(v.y) + sigf(v.z) + sigf(v.w);
    }

    // ---------- class BCE (whole grid, assignment recomputed per triple) ----
    for (int p = gt; p < NBCE_; p += GT) {
        const int b = p / (T_ * C_);
        const int r = p - b * (T_ * C_);
        const int t = r / C_;
        const int c = r - t * C_;
        float tc, tx, ty, tw, th;
        int besti, gi, gj;
        if (assign_target(tgt, b, t, tc, tx, ty, tw, th, besti, gi, gj)) {
            const int base = b * BSTR_ + besti * 85 * HW_ + gj * W_ + gi;
            const float pc = sigf(inp[base + (5 + c) * HW_]);
            const float oh = (c == (int)tc) ? 1.0f : 0.0f;
            acc -= oh * logf(pc) + (1.0f - oh) * log1pf(-pc);
        }
    }

    // ---------- per-batch target path (blocks 0..15, wave 0 only) ----------
    __shared__ int sh_cell[T_];
    float lcoord = 0.0f, vcnt = 0.0f, ucnt = 0.0f;
    if (bid < B_) {
        if (tid < T_) sh_cell[tid] = -1;
        if (tid < T_) {
            float tc, tx, ty, tw, th;
            int besti, gi, gj;
            const float* tp = tgt + (bid * T_ + tid) * 5;
            const float sum5 = tp[0] + tp[1] + tp[2] + tp[3] + tp[4];
            vcnt = (sum5 != 0.0f) ? 1.0f : 0.0f;
            if (assign_target(tgt, bid, tid, tc, tx, ty, tw, th, besti, gi, gj)) {
                sh_cell[tid] = (besti * H_ + gj) * W_ + gi;
                const int base = bid * BSTR_ + besti * 85 * HW_ + gj * W_ + gi;
                const float txt = tx * (float)W_ - (float)gi;
                const float tyt = ty * (float)H_ - (float)gj;
                const float twt = logf(tw * NETW_ / ANCH[2 * besti]);
                const float tht = logf(th * NETH_ / ANCH[2 * besti + 1]);
                const float scale = 2.0f * ty * tw;  // faithful: 2*t[2]*t[3]
                const float px = sigf(inp[base]);
                const float py = sigf(inp[base + HW_]);
                const float pw = inp[base + 2 * HW_];
                const float ph = inp[base + 3 * HW_];
                lcoord = scale * (fabsf(px - txt) + fabsf(py - tyt) +
                                  fabsf(pw - twt) + fabsf(ph - tht));
            }
        }
        __syncthreads();
        if (tid < T_ && sh_cell[tid] >= 0) {
            bool uniq = true;
            for (int q = 0; q < tid; ++q)
                if (sh_cell[q] == sh_cell[tid]) { uniq = false; break; }
            ucnt = uniq ? 1.0f : 0.0f;
        }
    }

    // ---------- reductions ----------
    __shared__ float red[4];
    const float r = waveRed(acc);
    if ((tid & 63) == 0) red[tid >> 6] = r;
    __syncthreads();
    if (tid == 0) ws[64 + bid] = red[0] + red[1] + red[2] + red[3];

    if (bid < B_) {
        // lcoord/vcnt/ucnt are nonzero only in lanes 0..49 => all in wave 0
        const float lr = waveRed(lcoord);
        const float vr = waveRed(vcnt);
        const float ur = waveRed(ucnt);
        if (tid == 0) {
            ws[bid]      = lr;
            ws[32 + bid] = vr;
            ws[48 + bid] = ur;
        }
    }
}

__global__ __launch_bounds__(256) void yolo_fin(const float* __restrict__ ws,
                                                float* __restrict__ out) {
    const int tid = threadIdx.x;
    float s = 0.0f;
    for (int i = tid; i < NB_; i += 256) s += ws[64 + i];
    __shared__ float red[4];
    const float r = waveRed(s);
    if ((tid & 63) == 0) red[tid >> 6] = r;
    __syncthreads();
    if (tid == 0) {
        const float conf_bce = red[0] + red[1] + red[2] + red[3];
        float lcoord = 0.f, vcnt = 0.f, ucnt = 0.f;
        for (int b = 0; b < B_; ++b) {
            lcoord += ws[b];
            vcnt   += ws[32 + b];
            ucnt   += ws[48 + b];
        }
        const float nt = fmaxf(vcnt, 1.0f);
        out[0] = (conf_bce - ucnt) + lcoord / nt;
    }
}

extern "C" void kernel_launch(void* const* d_in, const int* in_sizes, int n_in,
                              void* d_out, int out_size, void* d_ws, size_t ws_size,
                              hipStream_t stream) {
    const float* inp = (const float*)d_in[0];
    const float* tgt = (const float*)d_in[1];
    float* ws  = (float*)d_ws;
    float* out = (float*)d_out;

    yolo_main<<<NB_, 256, 0, stream>>>(inp, tgt, ws);
    yolo_fin<<<1, 256, 0, stream>>>(ws, out);
}

// Round 3
// 121.273 us; speedup vs baseline: 1.0334x; 1.0334x over previous
//
#include <hip/hip_runtime.h>

// Problem constants (from reference)
constexpr int B_  = 16;
constexpr int A_  = 3;     // MASK_SIZE
constexpr int C_  = 80;    // NUM_CLASSES
constexpr int T_  = 50;    // MAX_BOXES
constexpr int H_  = 76;
constexpr int W_  = 76;
constexpr int HW_ = H_ * W_;                  // 5776
constexpr int BSTR_ = A_ * (5 + C_) * HW_;    // 1472880 elements per batch
constexpr float NETW_ = 608.0f;
constexpr float NETH_ = 608.0f;

constexpr int NB_          = 256;             // total blocks (1 per CU)
constexpr int F4_PER_SLICE = HW_ / 4;         // 1444 float4 per conf plane
constexpr int CONF_F4      = B_ * A_ * F4_PER_SLICE;  // 69312
constexpr int NBCE_        = B_ * T_ * C_;    // 64000 (b,t,c) triples

constexpr unsigned MAGIC_ = 0x5ca1ab1eu;      // != 0xAAAAAAAA poison

__device__ const float ANCH[18] = {
    10.f, 13.f, 16.f, 30.f, 33.f, 23.f, 30.f, 61.f, 62.f,
    45.f, 59.f, 119.f, 116.f, 90.f, 156.f, 198.f, 373.f, 326.f};

__device__ __forceinline__ float sigf(float z) {
    return 1.0f / (1.0f + expf(-z));
}

__device__ __forceinline__ float waveRed(float v) {
    #pragma unroll
    for (int o = 32; o > 0; o >>= 1) v += __shfl_down(v, o);
    return v;
}

__device__ __forceinline__ void st_agent(float* p, float v) {
    __hip_atomic_store(p, v, __ATOMIC_RELAXED, __HIP_MEMORY_SCOPE_AGENT);
}
__device__ __forceinline__ float ld_agent(const float* p) {
    return __hip_atomic_load(p, __ATOMIC_RELAXED, __HIP_MEMORY_SCOPE_AGENT);
}

// Returns true if target (b,t) is assigned; must match reference argmax
// (first strict max wins).
__device__ __forceinline__ bool assign_target(const float* __restrict__ tgt,
                                              int b, int t,
                                              float& tc, float& tx, float& ty,
                                              float& tw, float& th,
                                              int& besti, int& gi, int& gj) {
    const float* tp = tgt + (b * T_ + t) * 5;
    tc = tp[0]; tx = tp[1]; ty = tp[2]; tw = tp[3]; th = tp[4];
    const bool valid = (tc + tx + ty + tw + th) != 0.0f;

    float bestv = -1.0f;
    besti = 0;
    #pragma unroll
    for (int k = 0; k < 9; ++k) {
        const float aw = ANCH[2 * k]     * (1.0f / NETW_);
        const float ah = ANCH[2 * k + 1] * (1.0f / NETH_);
        const float in = fminf(tw, aw) * fminf(th, ah);
        const float un = tw * th + aw * ah - in;
        const float iou = in / un;
        if (iou > bestv) { bestv = iou; besti = k; }
    }
    if (!(valid && besti < A_)) return false;

    gi = (int)(tx * (float)W_);
    gi = gi < 0 ? 0 : (gi > W_ - 1 ? W_ - 1 : gi);
    gj = (int)(ty * (float)H_);
    gj = gj < 0 ? 0 : (gj > H_ - 1 ? H_ - 1 : gj);
    return true;
}

// ws float layout:
//  [0..15]    lcoord per batch      (written by blocks 0..15)
//  [16..31]   valid count per batch
//  [32..47]   unique-cell count per batch
//  [64..319]  per-block acc partial (conf-sigmoid-sum + BCE)
//  [512..767] flags (as uint)
__global__ __launch_bounds__(256) void yolo_fused(const float* __restrict__ inp,
                                                  const float* __restrict__ tgt,
                                                  float* __restrict__ ws,
                                                  float* __restrict__ out) {
    const int tid = threadIdx.x;
    const int bid = blockIdx.x;
    const int gt  = bid * 256 + tid;
    constexpr int GT = NB_ * 256;  // 65536 threads
    unsigned* flags = reinterpret_cast<unsigned*>(ws) + 512;

    float acc = 0.0f;  // conf-sigmoid sum + class BCE (both additive in loss)

    // ---------- conf-channel sigmoid sum (whole grid) ----------
    for (int f = gt; f < CONF_F4; f += GT) {
        const int sl   = f / F4_PER_SLICE;
        const int pos4 = f - sl * F4_PER_SLICE;
        const int b    = sl / A_;
        const int a    = sl - b * A_;
        const float4 v = *reinterpret_cast<const float4*>(
            inp + b * BSTR_ + (a * 85 + 4) * HW_ + pos4 * 4);
        acc += sigf(v.x) + sigf(v.y) + sigf(v.z) + sigf(v.w);
    }

    // ---------- class BCE (whole grid, ≤1 triple per thread) ----------
    for (int p = gt; p < NBCE_; p += GT) {
        const int b = p / (T_ * C_);
        const int r = p - b * (T_ * C_);
        const int t = r / C_;
        const int c = r - t * C_;
        float tc, tx, ty, tw, th;
        int besti, gi, gj;
        if (assign_target(tgt, b, t, tc, tx, ty, tw, th, besti, gi, gj)) {
            const int base = b * BSTR_ + besti * 85 * HW_ + gj * W_ + gi;
            const float pc = sigf(inp[base + (5 + c) * HW_]);
            const float oh = (c == (int)tc) ? 1.0f : 0.0f;
            acc -= oh * logf(pc) + (1.0f - oh) * log1pf(-pc);
        }
    }

    // ---------- per-batch target path (blocks 0..15, wave 0 only) ----------
    __shared__ int sh_cell[T_];
    float lcoord = 0.0f, vcnt = 0.0f, ucnt = 0.0f;
    if (bid < B_) {
        if (tid < T_) sh_cell[tid] = -1;
        if (tid < T_) {
            float tc, tx, ty, tw, th;
            int besti, gi, gj;
            const float* tp = tgt + (bid * T_ + tid) * 5;
            const float sum5 = tp[0] + tp[1] + tp[2] + tp[3] + tp[4];
            vcnt = (sum5 != 0.0f) ? 1.0f : 0.0f;
            if (assign_target(tgt, bid, tid, tc, tx, ty, tw, th, besti, gi, gj)) {
                sh_cell[tid] = (besti * H_ + gj) * W_ + gi;
                const int base = bid * BSTR_ + besti * 85 * HW_ + gj * W_ + gi;
                const float txt = tx * (float)W_ - (float)gi;
                const float tyt = ty * (float)H_ - (float)gj;
                const float twt = logf(tw * NETW_ / ANCH[2 * besti]);
                const float tht = logf(th * NETH_ / ANCH[2 * besti + 1]);
                const float scale = 2.0f * ty * tw;  // faithful: 2*t[2]*t[3]
                const float px = sigf(inp[base]);
                const float py = sigf(inp[base + HW_]);
                const float pw = inp[base + 2 * HW_];
                const float ph = inp[base + 3 * HW_];
                lcoord = scale * (fabsf(px - txt) + fabsf(py - tyt) +
                                  fabsf(pw - twt) + fabsf(ph - tht));
            }
        }
        __syncthreads();
        if (tid < T_ && sh_cell[tid] >= 0) {
            bool uniq = true;
            for (int q = 0; q < tid; ++q)
                if (sh_cell[q] == sh_cell[tid]) { uniq = false; break; }
            ucnt = uniq ? 1.0f : 0.0f;
        }
    }

    // ---------- block-local reduction + partial publication ----------
    __shared__ float red[4];
    const float r = waveRed(acc);
    if ((tid & 63) == 0) red[tid >> 6] = r;
    // per-batch partials live entirely in wave 0 (lanes 0..49)
    const float lr = waveRed(lcoord);
    const float vr = waveRed(vcnt);
    const float ur = waveRed(ucnt);
    __syncthreads();
    if (tid == 0) {
        st_agent(&ws[64 + bid], red[0] + red[1] + red[2] + red[3]);
        if (bid < B_) {
            st_agent(&ws[bid],      lr);
            st_agent(&ws[16 + bid], vr);
            st_agent(&ws[32 + bid], ur);
        }
        __hip_atomic_store(&flags[bid], MAGIC_, __ATOMIC_RELEASE,
                           __HIP_MEMORY_SCOPE_AGENT);
    }

    // ---------- block NB_-1: wait for all partials, final combine ----------
    if (bid == NB_ - 1) {
        // each thread spins on one flag (incl. our own, already set)
        while (__hip_atomic_load(&flags[tid], __ATOMIC_ACQUIRE,
                                 __HIP_MEMORY_SCOPE_AGENT) != MAGIC_) {
            __builtin_amdgcn_s_sleep(1);
        }
        __syncthreads();

        float a = ld_agent(&ws[64 + tid]);  // acc partial for block `tid`
        __shared__ float red2[4];
        const float ra = waveRed(a);
        if ((tid & 63) == 0) red2[tid >> 6] = ra;

        // batch slots: lanes 0..47 of wave 0
        float lc = (tid < 16)               ? ld_agent(&ws[tid]) : 0.0f;
        float vc = (tid >= 16 && tid < 32)  ? ld_agent(&ws[tid]) : 0.0f;
        float uc = (tid >= 32 && tid < 48)  ? ld_agent(&ws[tid]) : 0.0f;
        const float lcs = waveRed(lc);
        const float vcs = waveRed(vc);
        const float ucs = waveRed(uc);
        __syncthreads();
        if (tid == 0) {
            const float conf_bce = red2[0] + red2[1] + red2[2] + red2[3];
            const float nt = fmaxf(vcs, 1.0f);
            out[0] = (conf_bce - ucs) + lcs / nt;
        }
    }
}

extern "C" void kernel_launch(void* const* d_in, const int* in_sizes, int n_in,
                              void* d_out, int out_size, void* d_ws, size_t ws_size,
                              hipStream_t stream) {
    const float* inp = (const float*)d_in[0];
    const float* tgt = (const float*)d_in[1];
    float* ws  = (float*)d_ws;
    float* out = (float*)d_out;

    yolo_fused<<<NB_, 256, 0, stream>>>(inp, tgt, ws, out);
}